// Round 1
// baseline (407.072 us; speedup 1.0000x reference)
//
#include <hip/hip_runtime.h>
#include <math.h>

// Problem constants (B=4, S=4096 -> 16384 tokens; H=4096; E=64; TOP_K=2)
#define TOKENS 16384
#define HDIM 4096
#define NE 64

// GEMM tiling
#define BM 128            // tokens per block
#define BK 32             // k per LDS chunk
#define KSPLIT 8          // K slices (partials reduced in kernel B)
#define KSLICE (HDIM / KSPLIT)   // 512

// Kernel A: partial logits P[ks][tok][e] = sum_{k in slice ks} A[tok,k]*W[e,k]
// 128 threads (2 waves), 8 tok x 8 exp micro-tile per thread (64 acc VGPRs).
// LDS reads: 4x ds_read_b128 per k per thread -> 64 B / 64 FMA = 1 B/FMA.
__global__ __launch_bounds__(128) void router_gemm(const float* __restrict__ A,
                                                   const float* __restrict__ W,
                                                   float* __restrict__ P) {
  __shared__ float As[BK][BM];   // k-major so 8 consecutive tokens are contiguous
  __shared__ float Ws[BK][NE];

  const int tid = threadIdx.x;
  const int bt = blockIdx.x;     // token tile
  const int ks = blockIdx.y;     // K slice
  const int tx = tid & 7;        // expert group: experts tx*8 .. tx*8+7
  const int ty = tid >> 3;       // token group: tokens ty*8 .. ty*8+7

  // A staging: thread tid owns token row (bt*BM + tid), loads BK floats/chunk.
  const float* Ab = A + (size_t)(bt * BM + tid) * HDIM + (size_t)ks * KSLICE;
  // W staging: thread pair per expert row; each thread 16 floats.
  const int we = tid >> 1;
  const int wk = (tid & 1) * 16;
  const float* Wb = W + (size_t)we * HDIM + (size_t)ks * KSLICE + wk;

  float acc[8][8];
#pragma unroll
  for (int i = 0; i < 8; ++i)
#pragma unroll
    for (int j = 0; j < 8; ++j) acc[i][j] = 0.f;

  for (int kc = 0; kc < KSLICE; kc += BK) {
    // ---- stage A (transposed to k-major). Writes: bank = tid%32 -> 2-way, free.
#pragma unroll
    for (int i = 0; i < BK / 4; ++i) {
      float4 v = *(const float4*)(Ab + kc + i * 4);
      As[i * 4 + 0][tid] = v.x;
      As[i * 4 + 1][tid] = v.y;
      As[i * 4 + 2][tid] = v.z;
      As[i * 4 + 3][tid] = v.w;
    }
    // ---- stage W
#pragma unroll
    for (int i = 0; i < 4; ++i) {
      float4 v = *(const float4*)(Wb + kc + i * 4);
      Ws[wk + i * 4 + 0][we] = v.x;
      Ws[wk + i * 4 + 1][we] = v.y;
      Ws[wk + i * 4 + 2][we] = v.z;
      Ws[wk + i * 4 + 3][we] = v.w;
    }
    __syncthreads();

#pragma unroll
    for (int k = 0; k < BK; ++k) {
      float a[8], w[8];
      *(float4*)&a[0] = *(const float4*)&As[k][ty * 8];
      *(float4*)&a[4] = *(const float4*)&As[k][ty * 8 + 4];
      *(float4*)&w[0] = *(const float4*)&Ws[k][tx * 8];
      *(float4*)&w[4] = *(const float4*)&Ws[k][tx * 8 + 4];
#pragma unroll
      for (int i = 0; i < 8; ++i)
#pragma unroll
        for (int j = 0; j < 8; ++j) acc[i][j] = fmaf(a[i], w[j], acc[i][j]);
    }
    __syncthreads();
  }

  // write partials P[ks][tok][e]
  float* Pb = P + ((size_t)ks * TOKENS + (size_t)bt * BM + ty * 8) * NE + tx * 8;
#pragma unroll
  for (int i = 0; i < 8; ++i) {
    float4 v0 = make_float4(acc[i][0], acc[i][1], acc[i][2], acc[i][3]);
    float4 v1 = make_float4(acc[i][4], acc[i][5], acc[i][6], acc[i][7]);
    *(float4*)(Pb + (size_t)i * NE) = v0;
    *(float4*)(Pb + (size_t)i * NE + 4) = v1;
  }
}

// Kernel B: one thread per token. Sum KSPLIT partial logit vectors, softmax,
// top-2 (strict > ascending == lowest-index tie-break like np/jax), renorm.
// Outputs concatenated: probs[16384*64] | indices[16384*2] | weights[16384*2].
__global__ __launch_bounds__(64) void router_finalize(const float* __restrict__ P,
                                                      float* __restrict__ out) {
  const int tok = blockIdx.x * 64 + threadIdx.x;
  float l[NE];

#pragma unroll
  for (int j = 0; j < NE / 4; ++j) {
    float4 v = *(const float4*)(P + (size_t)tok * NE + j * 4);
    l[j * 4 + 0] = v.x; l[j * 4 + 1] = v.y; l[j * 4 + 2] = v.z; l[j * 4 + 3] = v.w;
  }
#pragma unroll
  for (int s = 1; s < KSPLIT; ++s) {
    const float* ps = P + ((size_t)s * TOKENS + tok) * NE;
#pragma unroll
    for (int j = 0; j < NE / 4; ++j) {
      float4 v = *(const float4*)(ps + j * 4);
      l[j * 4 + 0] += v.x; l[j * 4 + 1] += v.y; l[j * 4 + 2] += v.z; l[j * 4 + 3] += v.w;
    }
  }

  float m = l[0];
#pragma unroll
  for (int e = 1; e < NE; ++e) m = fmaxf(m, l[e]);
  float sum = 0.f;
#pragma unroll
  for (int e = 0; e < NE; ++e) { l[e] = expf(l[e] - m); sum += l[e]; }
  const float inv = 1.f / sum;

  float v0 = -1.f, v1 = -1.f;
  int i0 = 0, i1 = 0;
#pragma unroll
  for (int e = 0; e < NE; ++e) {
    float p = l[e] * inv;
    l[e] = p;
    if (p > v0) { v1 = v0; i1 = i0; v0 = p; i0 = e; }
    else if (p > v1) { v1 = p; i1 = e; }
  }

  float* probs = out + (size_t)tok * NE;
#pragma unroll
  for (int j = 0; j < NE / 4; ++j)
    *(float4*)(probs + j * 4) =
        make_float4(l[j * 4 + 0], l[j * 4 + 1], l[j * 4 + 2], l[j * 4 + 3]);

  float* idxo = out + (size_t)TOKENS * NE + (size_t)tok * 2;
  idxo[0] = (float)i0;
  idxo[1] = (float)i1;

  float* wo = out + (size_t)TOKENS * NE + (size_t)TOKENS * 2 + (size_t)tok * 2;
  const float rs = 1.f / (v0 + v1);
  wo[0] = v0 * rs;
  wo[1] = v1 * rs;
}

extern "C" void kernel_launch(void* const* d_in, const int* in_sizes, int n_in,
                              void* d_out, int out_size, void* d_ws, size_t ws_size,
                              hipStream_t stream) {
  const float* A = (const float*)d_in[0];   // hidden_states [16384, 4096] f32
  const float* W = (const float*)d_in[1];   // gate_weight   [64, 4096] f32
  float* out = (float*)d_out;
  float* P = (float*)d_ws;                  // needs KSPLIT*16384*64*4 = 32 MiB

  dim3 gridA(TOKENS / BM, KSPLIT);          // 128 x 8 = 1024 blocks, 128 thr
  router_gemm<<<gridA, 128, 0, stream>>>(A, W, P);
  router_finalize<<<TOKENS / 64, 64, 0, stream>>>(P, out);
}

// Round 2
// 399.423 us; speedup vs baseline: 1.0192x; 1.0192x over previous
//
#include <hip/hip_runtime.h>
#include <math.h>

// B=4, S=4096 -> 16384 tokens; H=4096; E=64; TOP_K=2
#define TOKENS 16384
#define HDIM 4096
#define NE 64

#define BM 64                  // tokens per block
#define BK 32                  // k per LDS chunk
#define KSPLIT 8               // K slices
#define KSLICE (HDIM / KSPLIT) // 512
#define LDSP 68                // padded LDS row stride in floats (keeps b128 16B-aligned)

// GEMM: P[ks][tok][e] = sum_{k in slice} A[tok,k] * W[e,k]
// 256 threads (4 waves), 4x4 micro-tile -> 16 acc VGPRs, full-ish occupancy.
// LDS k-major with stride 68: compute reads are broadcast/2-way (free),
// staging writes 2-way (free). Staging global loads: 16x64B segments/wave.
__global__ __launch_bounds__(256, 4) void router_gemm(const float* __restrict__ A,
                                                      const float* __restrict__ W,
                                                      float* __restrict__ P) {
  __shared__ float As[BK * LDSP];  // [k][token_row]
  __shared__ float Ws[BK * LDSP];  // [k][expert_row]

  const int tid = threadIdx.x;
  const int bt = blockIdx.x;   // token tile (64 tokens)
  const int ks = blockIdx.y;   // K slice

  // staging map: row = tid>>2 (0..63), two float4 slots at cols (tid&3)*4 and +16
  const int sr = tid >> 2;
  const int sc = (tid & 3) * 4;

  const float* Ab = A + (size_t)(bt * BM + sr) * HDIM + (size_t)ks * KSLICE + sc;
  const float* Wb = W + (size_t)sr * HDIM + (size_t)ks * KSLICE + sc;  // sr<64 == E

  // compute map: tx = expert group (16), ty = token group (4 per wave)
  const int tx = tid & 15;
  const int ty = tid >> 4;

  float acc[4][4];
#pragma unroll
  for (int i = 0; i < 4; ++i)
#pragma unroll
    for (int j = 0; j < 4; ++j) acc[i][j] = 0.f;

  // register-buffered prefetch: load chunk 0
  float4 a0 = *(const float4*)(Ab);
  float4 a1 = *(const float4*)(Ab + 16);
  float4 w0 = *(const float4*)(Wb);
  float4 w1 = *(const float4*)(Wb + 16);

  for (int kc = 0; kc < KSLICE; kc += BK) {
    // stage current chunk from registers (writes: 2 lanes/bank -> free)
    As[(sc + 0) * LDSP + sr] = a0.x;
    As[(sc + 1) * LDSP + sr] = a0.y;
    As[(sc + 2) * LDSP + sr] = a0.z;
    As[(sc + 3) * LDSP + sr] = a0.w;
    As[(sc + 16) * LDSP + sr] = a1.x;
    As[(sc + 17) * LDSP + sr] = a1.y;
    As[(sc + 18) * LDSP + sr] = a1.z;
    As[(sc + 19) * LDSP + sr] = a1.w;
    Ws[(sc + 0) * LDSP + sr] = w0.x;
    Ws[(sc + 1) * LDSP + sr] = w0.y;
    Ws[(sc + 2) * LDSP + sr] = w0.z;
    Ws[(sc + 3) * LDSP + sr] = w0.w;
    Ws[(sc + 16) * LDSP + sr] = w1.x;
    Ws[(sc + 17) * LDSP + sr] = w1.y;
    Ws[(sc + 18) * LDSP + sr] = w1.z;
    Ws[(sc + 19) * LDSP + sr] = w1.w;
    __syncthreads();

    // prefetch next chunk into registers (overlaps with compute below)
    if (kc + BK < KSLICE) {
      a0 = *(const float4*)(Ab + kc + BK);
      a1 = *(const float4*)(Ab + kc + BK + 16);
      w0 = *(const float4*)(Wb + kc + BK);
      w1 = *(const float4*)(Wb + kc + BK + 16);
    }

#pragma unroll
    for (int k = 0; k < BK; ++k) {
      float4 av = *(const float4*)&As[k * LDSP + ty * 4];  // 4 addrs/wave: broadcast
      float4 wv = *(const float4*)&Ws[k * LDSP + tx * 4];  // 2 addrs/bank: free
      const float a[4] = {av.x, av.y, av.z, av.w};
      const float w[4] = {wv.x, wv.y, wv.z, wv.w};
#pragma unroll
      for (int i = 0; i < 4; ++i)
#pragma unroll
        for (int j = 0; j < 4; ++j) acc[i][j] = fmaf(a[i], w[j], acc[i][j]);
    }
    __syncthreads();
  }

  // write partials P[ks][tok][e]; per-wave: 4 segments of 256B -> coalesced
  float* Pb = P + ((size_t)ks * TOKENS + (size_t)bt * BM + ty * 4) * NE + tx * 4;
#pragma unroll
  for (int i = 0; i < 4; ++i)
    *(float4*)(Pb + (size_t)i * NE) =
        make_float4(acc[i][0], acc[i][1], acc[i][2], acc[i][3]);
}

// Finalize: wave = token, lane = expert. Coalesced partial-sum reads,
// shuffle softmax + top-2 (ballot lowest-index tie-break == np/jax).
__global__ __launch_bounds__(256) void router_finalize(const float* __restrict__ P,
                                                       float* __restrict__ out) {
  const int lane = threadIdx.x & 63;
  const int wave = threadIdx.x >> 6;
  const int tok = blockIdx.x * 4 + wave;

  float l = 0.f;
#pragma unroll
  for (int s = 0; s < KSPLIT; ++s)
    l += P[((size_t)s * TOKENS + tok) * NE + lane];

  float m = l;
#pragma unroll
  for (int off = 32; off >= 1; off >>= 1) m = fmaxf(m, __shfl_xor(m, off, 64));

  const float e = expf(l - m);
  float sum = e;
#pragma unroll
  for (int off = 32; off >= 1; off >>= 1) sum += __shfl_xor(sum, off, 64);

  const float p = e / sum;
  out[(size_t)tok * NE + lane] = p;

  // top-2 over p across lanes
  float m0 = p;
#pragma unroll
  for (int off = 32; off >= 1; off >>= 1) m0 = fmaxf(m0, __shfl_xor(m0, off, 64));
  const unsigned long long b0 = __ballot(p == m0);
  const int i0 = __ffsll(b0) - 1;

  const float pm = (lane == i0) ? -1.f : p;
  float m1 = pm;
#pragma unroll
  for (int off = 32; off >= 1; off >>= 1) m1 = fmaxf(m1, __shfl_xor(m1, off, 64));
  const unsigned long long b1 = __ballot(pm == m1);
  const int i1 = __ffsll(b1) - 1;

  if (lane == 0) {
    float* idxo = out + (size_t)TOKENS * NE + (size_t)tok * 2;
    idxo[0] = (float)i0;
    idxo[1] = (float)i1;
    float* wo = out + (size_t)TOKENS * NE + (size_t)TOKENS * 2 + (size_t)tok * 2;
    const float d = m0 + m1;
    wo[0] = m0 / d;
    wo[1] = m1 / d;
  }
}

extern "C" void kernel_launch(void* const* d_in, const int* in_sizes, int n_in,
                              void* d_out, int out_size, void* d_ws, size_t ws_size,
                              hipStream_t stream) {
  const float* A = (const float*)d_in[0];  // hidden_states [16384, 4096] f32
  const float* W = (const float*)d_in[1];  // gate_weight   [64, 4096] f32
  float* out = (float*)d_out;
  float* P = (float*)d_ws;                 // 8*16384*64*4 = 32 MiB partials

  dim3 gridA(TOKENS / BM, KSPLIT);         // 256 x 8 = 2048 blocks, 256 thr
  router_gemm<<<gridA, 256, 0, stream>>>(A, W, P);
  router_finalize<<<TOKENS / 4, 256, 0, stream>>>(P, out);
}